// Round 3
// baseline (621.431 us; speedup 1.0000x reference)
//
#include <hip/hip_runtime.h>

typedef __bf16 bf16;
typedef __bf16 bf16x8 __attribute__((ext_vector_type(8)));
typedef __bf16 bf16x4 __attribute__((ext_vector_type(4)));
typedef float f32x4 __attribute__((ext_vector_type(4)));

constexpr int NB   = 32;
constexpr int CIN  = 1024;
constexpr int CB   = 256;
constexpr int COUT = 1024;
constexpr int HW   = 784;
constexpr int WIMG = 28;

__device__ __forceinline__ bf16x8 fload(const bf16* p) {
  return *reinterpret_cast<const bf16x8*>(p);
}

__device__ __forceinline__ bf16x8 fzero() {
  bf16x8 z;
#pragma unroll
  for (int i = 0; i < 8; ++i) z[i] = (bf16)0.0f;
  return z;
}

// ---------------- sentinel fill: out <- 0.25f (diagnostic: distinguishes
// "no kernel ran" (absmax 5.34375) from "conv3 didn't run" (absmax 5.09375))
__global__ __launch_bounds__(256) void k_fill(float* __restrict__ o, int n) {
  int i = (blockIdx.x * 256 + threadIdx.x) * 4;
  if (i < n) {
    float4 v = {0.25f, 0.25f, 0.25f, 0.25f};
    *reinterpret_cast<float4*>(o + i) = v;
  }
}

// ---------------- x: fp32 NCHW -> bf16 NHWC (per batch: 1024 x 784 -> 784 x 1024)
__global__ __launch_bounds__(256) void k_transpose(const float* __restrict__ x,
                                                   bf16* __restrict__ xT) {
  __shared__ bf16 tile[64][73];  // [ci_local][p_local], pad to spread banks
  const int nb = blockIdx.z;
  const int p0 = blockIdx.x * 64;   // gridDim.x = 13
  const int c0 = blockIdx.y * 64;   // gridDim.y = 16
  const int tid = threadIdx.x;
#pragma unroll
  for (int it = 0; it < 4; ++it) {
    int idx = tid + it * 256;       // [0,1024): 64 rows x 16 float4-chunks
    int row = idx >> 4, c4 = idx & 15;
    int p = p0 + c4 * 4;
    if (p < HW) {                   // 784 % 4 == 0
      float4 v = *reinterpret_cast<const float4*>(x + (nb * CIN + c0 + row) * HW + p);
      tile[row][c4 * 4 + 0] = (bf16)v.x;
      tile[row][c4 * 4 + 1] = (bf16)v.y;
      tile[row][c4 * 4 + 2] = (bf16)v.z;
      tile[row][c4 * 4 + 3] = (bf16)v.w;
    }
  }
  __syncthreads();
#pragma unroll
  for (int it = 0; it < 2; ++it) {
    int idx = tid + it * 256;       // [0,512): 64 p-rows x 8 bf16x8-chunks
    int pr = idx >> 3, c8 = idx & 7;
    if (p0 + pr < HW) {
      bf16x8 v;
#pragma unroll
      for (int j = 0; j < 8; ++j) v[j] = tile[c8 * 8 + j][pr];
      *reinterpret_cast<bf16x8*>(xT + (nb * HW + p0 + pr) * CIN + c0 + c8 * 8) = v;
    }
  }
}

// ---------------- w2: fp32 [co][ci][r][s] -> bf16 [co][rs][ci]
__global__ __launch_bounds__(256) void k_w2r(const float* __restrict__ w2,
                                             bf16* __restrict__ w2r) {
  int i = blockIdx.x * 256 + threadIdx.x;  // i = (co*9 + rs)*256 + ci
  if (i < CB * 9 * CB) {
    int ci = i & 255;
    int t = i >> 8;
    int rs = t % 9;
    int co = t / 9;
    w2r[i] = (bf16)w2[(co * CB + ci) * 9 + rs];
  }
}

// ---------------- generic fp32 -> bf16 cast (n multiple of 4)
__global__ __launch_bounds__(256) void k_cast(const float* __restrict__ a,
                                              bf16* __restrict__ o, int n) {
  int i = (blockIdx.x * 256 + threadIdx.x) * 4;
  if (i < n) {
    float4 v = *reinterpret_cast<const float4*>(a + i);
    bf16x4 w;
    w[0] = (bf16)v.x; w[1] = (bf16)v.y; w[2] = (bf16)v.z; w[3] = (bf16)v.w;
    *reinterpret_cast<bf16x4*>(o + i) = w;
  }
}

// ---------------- conv1: out1[p][co] = relu(s1*Sum_ci xT[p][ci]*w1[co][ci] + b1)
// GEMM-BT: M=784 (p, predicated), N=256 (co), K=1024. Block 64x128, 4 waves 2x2.
__global__ __launch_bounds__(256) void k_conv1(const bf16* __restrict__ xT,
                                               const bf16* __restrict__ w1,
                                               const float* __restrict__ s1,
                                               const float* __restrict__ b1,
                                               bf16* __restrict__ out1) {
  const int nb = blockIdx.z;
  const int tid = threadIdx.x;
  const int wave = tid >> 6, lane = tid & 63;
  const int quad = lane >> 4, l16 = lane & 15;
  const int m0 = blockIdx.x * 64 + (wave >> 1) * 32;
  const int n0 = blockIdx.y * 128 + (wave & 1) * 64;

  const bf16* A = xT + nb * HW * CIN;
  const bf16* pa[2];
  const bf16* pb[4];
#pragma unroll
  for (int mi = 0; mi < 2; ++mi) {
    int m = min(m0 + mi * 16 + l16, HW - 1);  // clamp: garbage rows never stored
    pa[mi] = A + m * CIN + quad * 8;
  }
#pragma unroll
  for (int ni = 0; ni < 4; ++ni)
    pb[ni] = w1 + (n0 + ni * 16 + l16) * CIN + quad * 8;

  f32x4 acc[2][4];
#pragma unroll
  for (int mi = 0; mi < 2; ++mi)
#pragma unroll
    for (int ni = 0; ni < 4; ++ni) acc[mi][ni] = {0.f, 0.f, 0.f, 0.f};

  for (int k = 0; k < CIN; k += 32) {
    bf16x8 a[2], b[4];
#pragma unroll
    for (int mi = 0; mi < 2; ++mi) a[mi] = fload(pa[mi] + k);
#pragma unroll
    for (int ni = 0; ni < 4; ++ni) b[ni] = fload(pb[ni] + k);
#pragma unroll
    for (int mi = 0; mi < 2; ++mi)
#pragma unroll
      for (int ni = 0; ni < 4; ++ni)
        acc[mi][ni] = __builtin_amdgcn_mfma_f32_16x16x32_bf16(a[mi], b[ni], acc[mi][ni], 0, 0, 0);
  }

  bf16* O = out1 + nb * HW * CB;
#pragma unroll
  for (int ni = 0; ni < 4; ++ni) {
    int n = n0 + ni * 16 + l16;
    float sv = s1[n], bv = b1[n];
#pragma unroll
    for (int mi = 0; mi < 2; ++mi)
#pragma unroll
      for (int r = 0; r < 4; ++r) {
        int m = m0 + mi * 16 + quad * 4 + r;
        if (m < HW) {
          float v = fmaxf(acc[mi][ni][r] * sv + bv, 0.f);
          O[m * CB + n] = (bf16)v;
        }
      }
  }
}

// ---------------- conv2: 3x3 SAME, implicit GEMM. M=784 (p), N=256 (co), K=9*256.
__global__ __launch_bounds__(256) void k_conv2(const bf16* __restrict__ in1,
                                               const bf16* __restrict__ w2r,
                                               const float* __restrict__ s2,
                                               const float* __restrict__ b2,
                                               bf16* __restrict__ out2) {
  const int nb = blockIdx.z;
  const int tid = threadIdx.x;
  const int wave = tid >> 6, lane = tid & 63;
  const int quad = lane >> 4, l16 = lane & 15;
  const int m0 = blockIdx.x * 64 + (wave >> 1) * 32;
  const int n0 = blockIdx.y * 128 + (wave & 1) * 64;

  int hh[2], ww[2];
  bool inb[2];
  const bf16* pa0[2];
#pragma unroll
  for (int mi = 0; mi < 2; ++mi) {
    int m = m0 + mi * 16 + l16;
    inb[mi] = m < HW;
    int mc = min(m, HW - 1);
    hh[mi] = mc / WIMG;
    ww[mi] = mc % WIMG;
    pa0[mi] = in1 + (nb * HW + mc) * CB + quad * 8;
  }
  const bf16* pb0[4];
#pragma unroll
  for (int ni = 0; ni < 4; ++ni)
    pb0[ni] = w2r + (n0 + ni * 16 + l16) * (9 * CB) + quad * 8;

  f32x4 acc[2][4];
#pragma unroll
  for (int mi = 0; mi < 2; ++mi)
#pragma unroll
    for (int ni = 0; ni < 4; ++ni) acc[mi][ni] = {0.f, 0.f, 0.f, 0.f};

  const bf16x8 z = fzero();

#pragma unroll
  for (int rs = 0; rs < 9; ++rs) {
    const int r = rs / 3, s = rs % 3;
    const int aoff = ((r - 1) * WIMG + (s - 1)) * CB;
    const int boff = rs * CB;
    bool v[2];
#pragma unroll
    for (int mi = 0; mi < 2; ++mi) {
      int h2 = hh[mi] + r - 1, w2_ = ww[mi] + s - 1;
      v[mi] = inb[mi] && ((unsigned)h2 < WIMG) && ((unsigned)w2_ < WIMG);
    }
    for (int k = 0; k < CB; k += 32) {
      bf16x8 a[2], b[4];
#pragma unroll
      for (int mi = 0; mi < 2; ++mi) a[mi] = v[mi] ? fload(pa0[mi] + aoff + k) : z;
#pragma unroll
      for (int ni = 0; ni < 4; ++ni) b[ni] = fload(pb0[ni] + boff + k);
#pragma unroll
      for (int mi = 0; mi < 2; ++mi)
#pragma unroll
        for (int ni = 0; ni < 4; ++ni)
          acc[mi][ni] = __builtin_amdgcn_mfma_f32_16x16x32_bf16(a[mi], b[ni], acc[mi][ni], 0, 0, 0);
    }
  }

  bf16* O = out2 + nb * HW * CB;
#pragma unroll
  for (int ni = 0; ni < 4; ++ni) {
    int n = n0 + ni * 16 + l16;
    float sv = s2[n], bv = b2[n];
#pragma unroll
    for (int mi = 0; mi < 2; ++mi)
#pragma unroll
      for (int r = 0; r < 4; ++r) {
        int m = m0 + mi * 16 + quad * 4 + r;
        if (m < HW) {
          float v = fmaxf(acc[mi][ni][r] * sv + bv, 0.f);
          O[m * CB + n] = (bf16)v;
        }
      }
  }
}

// ---------------- conv3: out[co][p] = relu(s3*Sum_ci out2[p][ci]*w3[co][ci] + b3 + x[co][p])
// GEMM-BT: M=1024 (co), N=784 (p, predicated), K=256. FP32 NCHW output + fp32 residual.
__global__ __launch_bounds__(256) void k_conv3(const bf16* __restrict__ in2,
                                               const bf16* __restrict__ w3,
                                               const float* __restrict__ s3,
                                               const float* __restrict__ b3,
                                               const float* __restrict__ x,
                                               float* __restrict__ out) {
  const int nb = blockIdx.z;
  const int tid = threadIdx.x;
  const int wave = tid >> 6, lane = tid & 63;
  const int quad = lane >> 4, l16 = lane & 15;
  const int m0 = blockIdx.x * 64 + (wave >> 1) * 32;   // co
  const int n0 = blockIdx.y * 128 + (wave & 1) * 64;   // p (gridDim.y = 7)

  const bf16* Bb = in2 + nb * HW * CB;
  const bf16* pa[2];
  const bf16* pb[4];
  int ncol[4];
#pragma unroll
  for (int mi = 0; mi < 2; ++mi)
    pa[mi] = w3 + (m0 + mi * 16 + l16) * CB + quad * 8;
#pragma unroll
  for (int ni = 0; ni < 4; ++ni) {
    ncol[ni] = n0 + ni * 16 + l16;
    pb[ni] = Bb + min(ncol[ni], HW - 1) * CB + quad * 8;  // clamp: garbage cols never stored
  }

  f32x4 acc[2][4];
#pragma unroll
  for (int mi = 0; mi < 2; ++mi)
#pragma unroll
    for (int ni = 0; ni < 4; ++ni) acc[mi][ni] = {0.f, 0.f, 0.f, 0.f};

  for (int k = 0; k < CB; k += 32) {
    bf16x8 a[2], b[4];
#pragma unroll
    for (int mi = 0; mi < 2; ++mi) a[mi] = fload(pa[mi] + k);
#pragma unroll
    for (int ni = 0; ni < 4; ++ni) b[ni] = fload(pb[ni] + k);
#pragma unroll
    for (int mi = 0; mi < 2; ++mi)
#pragma unroll
      for (int ni = 0; ni < 4; ++ni)
        acc[mi][ni] = __builtin_amdgcn_mfma_f32_16x16x32_bf16(a[mi], b[ni], acc[mi][ni], 0, 0, 0);
  }

#pragma unroll
  for (int mi = 0; mi < 2; ++mi)
#pragma unroll
    for (int r = 0; r < 4; ++r) {
      int m = m0 + mi * 16 + quad * 4 + r;
      float sv = s3[m], bv = b3[m];
      const float* xrow = x + (nb * COUT + m) * HW;
      float* orow = out + (nb * COUT + m) * HW;
#pragma unroll
      for (int ni = 0; ni < 4; ++ni) {
        int n = ncol[ni];
        if (n < HW) {
          float v = acc[mi][ni][r] * sv + bv + xrow[n];
          orow[n] = fmaxf(v, 0.f);
        }
      }
    }
}

extern "C" void kernel_launch(void* const* d_in, const int* in_sizes, int n_in,
                              void* d_out, int out_size, void* d_ws, size_t ws_size,
                              hipStream_t stream) {
  const float* x  = (const float*)d_in[0];
  const float* w1 = (const float*)d_in[1];
  const float* w2 = (const float*)d_in[2];
  const float* w3 = (const float*)d_in[3];
  const float* s1 = (const float*)d_in[4];
  const float* b1 = (const float*)d_in[5];
  const float* s2 = (const float*)d_in[6];
  const float* b2 = (const float*)d_in[7];
  const float* s3 = (const float*)d_in[8];
  const float* b3 = (const float*)d_in[9];
  float* out = (float*)d_out;

  char* ws = (char*)d_ws;
  // workspace layout (bytes):
  // xT 51,380,224 | o1 12,845,056 | o2 12,845,056 | w2r 1,179,648 | w1b 524,288 | w3b 524,288
  bf16* xT  = (bf16*)(ws);
  bf16* o1  = (bf16*)(ws + 51380224);
  bf16* o2  = (bf16*)(ws + 64225280);
  bf16* w2r = (bf16*)(ws + 77070336);
  bf16* w1b = (bf16*)(ws + 78249984);
  bf16* w3b = (bf16*)(ws + 78774272);

  k_fill<<<dim3((out_size / 4 + 255) / 256, 1, 1), 256, 0, stream>>>(out, out_size);
  k_transpose<<<dim3(13, 16, NB), 256, 0, stream>>>(x, xT);
  k_w2r<<<dim3((CB * 9 * CB + 255) / 256, 1, 1), 256, 0, stream>>>(w2, w2r);
  k_cast<<<dim3(256, 1, 1), 256, 0, stream>>>(w1, w1b, CB * CIN);
  k_cast<<<dim3(256, 1, 1), 256, 0, stream>>>(w3, w3b, COUT * CB);
  k_conv1<<<dim3(13, 2, NB), 256, 0, stream>>>(xT, w1b, s1, b1, o1);
  k_conv2<<<dim3(13, 2, NB), 256, 0, stream>>>(o1, w2r, s2, b2, o2);
  k_conv3<<<dim3(16, 7, NB), 256, 0, stream>>>(o2, w3b, s3, b3, x, out);
}

// Round 4
// 392.772 us; speedup vs baseline: 1.5822x; 1.5822x over previous
//
#include <hip/hip_runtime.h>
#include <stdint.h>

typedef __bf16 bf16;
typedef __bf16 bf16x8 __attribute__((ext_vector_type(8)));
typedef __bf16 bf16x4 __attribute__((ext_vector_type(4)));
typedef float f32x4 __attribute__((ext_vector_type(4)));

constexpr int NB   = 32;
constexpr int CIN  = 1024;
constexpr int CB   = 256;
constexpr int COUT = 1024;
constexpr int HW   = 784;
constexpr int WIMG = 28;
constexpr int PW   = 30;    // padded width (28+2)
constexpr int PHW  = 900;   // padded pixels per image (30*30)

typedef const __attribute__((address_space(1))) void GV;
typedef __attribute__((address_space(3))) void LV;

// async global->LDS, 16B/lane. LDS dest = uniform base + lane*16 (HW rule);
// global src is per-lane (gather). AMDGPU addrspacecast flat->local = low 32 bits.
__device__ __forceinline__ void gl16(const void* g, void* l) {
  __builtin_amdgcn_global_load_lds((GV*)(uintptr_t)g,
                                   (LV*)(uint32_t)(uintptr_t)l, 16, 0, 0);
}

// ---------------- zero padded o1p buffer (border must be 0; ws re-poisoned each call)
__global__ __launch_bounds__(256) void k_zero(uint4* __restrict__ p, int n) {
  int i = blockIdx.x * 256 + threadIdx.x;
  if (i < n) { uint4 z; z.x = z.y = z.z = z.w = 0u; p[i] = z; }
}

// ---------------- x: fp32 NCHW -> bf16 NHWC (per batch: 1024 x 784 -> 784 x 1024)
__global__ __launch_bounds__(256) void k_transpose(const float* __restrict__ x,
                                                   bf16* __restrict__ xT) {
  __shared__ bf16 tile[64][73];
  const int nb = blockIdx.z;
  const int p0 = blockIdx.x * 64;   // 13
  const int c0 = blockIdx.y * 64;   // 16
  const int tid = threadIdx.x;
#pragma unroll
  for (int it = 0; it < 4; ++it) {
    int idx = tid + it * 256;
    int row = idx >> 4, c4 = idx & 15;
    int p = p0 + c4 * 4;
    if (p < HW) {
      float4 v = *reinterpret_cast<const float4*>(x + (nb * CIN + c0 + row) * HW + p);
      tile[row][c4 * 4 + 0] = (bf16)v.x;
      tile[row][c4 * 4 + 1] = (bf16)v.y;
      tile[row][c4 * 4 + 2] = (bf16)v.z;
      tile[row][c4 * 4 + 3] = (bf16)v.w;
    }
  }
  __syncthreads();
#pragma unroll
  for (int it = 0; it < 2; ++it) {
    int idx = tid + it * 256;
    int pr = idx >> 3, c8 = idx & 7;
    if (p0 + pr < HW) {
      bf16x8 v;
#pragma unroll
      for (int j = 0; j < 8; ++j) v[j] = tile[c8 * 8 + j][pr];
      *reinterpret_cast<bf16x8*>(xT + (nb * HW + p0 + pr) * CIN + c0 + c8 * 8) = v;
    }
  }
}

// ---------------- w2: fp32 [co][ci][3][3] -> bf16 [co][rs][ci]
__global__ __launch_bounds__(256) void k_w2r(const float* __restrict__ w2,
                                             bf16* __restrict__ w2r) {
  int i = blockIdx.x * 256 + threadIdx.x;
  if (i < CB * 9 * CB) {
    int ci = i & 255;
    int t = i >> 8;
    int rs = t % 9;
    int co = t / 9;
    w2r[i] = (bf16)w2[(co * CB + ci) * 9 + rs];
  }
}

// ---------------- fp32 -> bf16 cast
__global__ __launch_bounds__(256) void k_cast(const float* __restrict__ a,
                                              bf16* __restrict__ o, int n) {
  int i = (blockIdx.x * 256 + threadIdx.x) * 4;
  if (i < n) {
    float4 v = *reinterpret_cast<const float4*>(a + i);
    bf16x4 w;
    w[0] = (bf16)v.x; w[1] = (bf16)v.y; w[2] = (bf16)v.z; w[3] = (bf16)v.w;
    *reinterpret_cast<bf16x4*>(o + i) = w;
  }
}

// =====================================================================
// GEMM structure (all 3 convs): block = 256 thr (4 waves 2x2), block tile
// 128x128, wave tile 64x64 (4x4 frags 16x16x32), BK=64.
// LDS layout = fragment order: 16 groups of 1KB per tile; group g=(rowgrp,half),
// within group lane order (l16=row, quad=kchunk) -> every ds_read_b128 is
// base+lane*16 (conflict-free) and global_load_lds staging is lane-linear.
// =====================================================================

// ---------------- conv1: o1p[pad(m)][co] = relu(s1*xT[m][:]·w1[co][:]+b1)
__global__ __launch_bounds__(256, 2) void k_conv1(const bf16* __restrict__ xT,
                                                  const bf16* __restrict__ w1,
                                                  const float* __restrict__ s1,
                                                  const float* __restrict__ b1,
                                                  bf16* __restrict__ o1p) {
  __shared__ char smem[32768];
  char* const As = smem;
  char* const Bs = smem + 16384;
  const int tid = threadIdx.x, wave = tid >> 6, lane = tid & 63;
  const int quad = lane >> 4, l16 = lane & 15;
  const int wr = wave >> 1, wc = wave & 1;
  const int Mt = blockIdx.x, Nt = blockIdx.y;

  const bf16* gb[8];
  char* lb;
  if (wave < 2) {
    lb = As + wave * 8192;
#pragma unroll
    for (int i = 0; i < 8; ++i) {
      int g = wave * 8 + i;
      int m = Mt * 128 + (g >> 1) * 16 + l16;
      gb[i] = xT + (size_t)m * CIN + ((g & 1) * 4 + quad) * 8;
    }
  } else {
    lb = Bs + (wave - 2) * 8192;
#pragma unroll
    for (int i = 0; i < 8; ++i) {
      int g = (wave - 2) * 8 + i;
      int n = Nt * 128 + (g >> 1) * 16 + l16;
      gb[i] = w1 + (size_t)n * CIN + ((g & 1) * 4 + quad) * 8;
    }
  }

  f32x4 acc[4][4];
#pragma unroll
  for (int i = 0; i < 4; ++i)
#pragma unroll
    for (int j = 0; j < 4; ++j) acc[i][j] = {0.f, 0.f, 0.f, 0.f};

  const int lo = lane * 16;
  for (int s = 0; s < CIN / 64; ++s) {
#pragma unroll
    for (int i = 0; i < 8; ++i) gl16(gb[i] + s * 64, lb + i * 1024);
    __syncthreads();
    bf16x8 a[4][2], b[4][2];
#pragma unroll
    for (int mi = 0; mi < 4; ++mi)
#pragma unroll
      for (int h = 0; h < 2; ++h)
        a[mi][h] = *(const bf16x8*)(As + (((wr * 4 + mi) * 2 + h) * 1024) + lo);
#pragma unroll
    for (int ni = 0; ni < 4; ++ni)
#pragma unroll
      for (int h = 0; h < 2; ++h)
        b[ni][h] = *(const bf16x8*)(Bs + (((wc * 4 + ni) * 2 + h) * 1024) + lo);
#pragma unroll
    for (int h = 0; h < 2; ++h)
#pragma unroll
      for (int mi = 0; mi < 4; ++mi)
#pragma unroll
        for (int ni = 0; ni < 4; ++ni)
          acc[mi][ni] = __builtin_amdgcn_mfma_f32_16x16x32_bf16(a[mi][h], b[ni][h], acc[mi][ni], 0, 0, 0);
    __syncthreads();
  }

  float sv[4], bv[4];
  const int nb0 = Nt * 128 + wc * 64;
#pragma unroll
  for (int ni = 0; ni < 4; ++ni) { int n = nb0 + ni * 16 + l16; sv[ni] = s1[n]; bv[ni] = b1[n]; }
#pragma unroll
  for (int mi = 0; mi < 4; ++mi)
#pragma unroll
    for (int r = 0; r < 4; ++r) {
      int m = Mt * 128 + wr * 64 + mi * 16 + quad * 4 + r;
      int nbi = m / HW, p = m - nbi * HW;
      int hh = p / WIMG, ww = p - hh * WIMG;
      bf16* dst = o1p + ((size_t)nbi * PHW + (hh + 1) * PW + (ww + 1)) * CB;
#pragma unroll
      for (int ni = 0; ni < 4; ++ni) {
        int n = nb0 + ni * 16 + l16;
        dst[n] = (bf16)fmaxf(acc[mi][ni][r] * sv[ni] + bv[ni], 0.f);
      }
    }
}

// ---------------- conv2: 3x3 SAME over padded o1p, K = 9*256, 36 BK64 steps
__global__ __launch_bounds__(256, 2) void k_conv2(const bf16* __restrict__ o1p,
                                                  const bf16* __restrict__ w2r,
                                                  const float* __restrict__ s2,
                                                  const float* __restrict__ b2,
                                                  bf16* __restrict__ o2) {
  __shared__ char smem[32768];
  char* const As = smem;
  char* const Bs = smem + 16384;
  const int tid = threadIdx.x, wave = tid >> 6, lane = tid & 63;
  const int quad = lane >> 4, l16 = lane & 15;
  const int wr = wave >> 1, wc = wave & 1;
  const int Mt = blockIdx.x, Nt = blockIdx.y;

  const bf16* gb[8];
  char* lb;
  if (wave < 2) {
    lb = As + wave * 8192;
#pragma unroll
    for (int i = 0; i < 8; ++i) {
      int g = wave * 8 + i;
      int m = Mt * 128 + (g >> 1) * 16 + l16;
      int nbi = m / HW, p = m - nbi * HW;
      int hh = p / WIMG, ww = p - hh * WIMG;
      int pp = nbi * PHW + (hh + 1) * PW + (ww + 1);
      gb[i] = o1p + (size_t)pp * CB + ((g & 1) * 4 + quad) * 8;
    }
  } else {
    lb = Bs + (wave - 2) * 8192;
#pragma unroll
    for (int i = 0; i < 8; ++i) {
      int g = (wave - 2) * 8 + i;
      int n = Nt * 128 + (g >> 1) * 16 + l16;
      gb[i] = w2r + (size_t)n * (9 * CB) + ((g & 1) * 4 + quad) * 8;
    }
  }

  f32x4 acc[4][4];
#pragma unroll
  for (int i = 0; i < 4; ++i)
#pragma unroll
    for (int j = 0; j < 4; ++j) acc[i][j] = {0.f, 0.f, 0.f, 0.f};

  const int lo = lane * 16;
  for (int s = 0; s < 36; ++s) {
    int rs = s >> 2;
    int aoff = ((rs / 3) - 1) * PW + (rs % 3) - 1;        // spatial halo offset (padded px)
    int soff = (wave < 2) ? (aoff * CB + (s & 3) * 64) : (s * 64);
#pragma unroll
    for (int i = 0; i < 8; ++i) gl16(gb[i] + soff, lb + i * 1024);
    __syncthreads();
    bf16x8 a[4][2], b[4][2];
#pragma unroll
    for (int mi = 0; mi < 4; ++mi)
#pragma unroll
      for (int h = 0; h < 2; ++h)
        a[mi][h] = *(const bf16x8*)(As + (((wr * 4 + mi) * 2 + h) * 1024) + lo);
#pragma unroll
    for (int ni = 0; ni < 4; ++ni)
#pragma unroll
      for (int h = 0; h < 2; ++h)
        b[ni][h] = *(const bf16x8*)(Bs + (((wc * 4 + ni) * 2 + h) * 1024) + lo);
#pragma unroll
    for (int h = 0; h < 2; ++h)
#pragma unroll
      for (int mi = 0; mi < 4; ++mi)
#pragma unroll
        for (int ni = 0; ni < 4; ++ni)
          acc[mi][ni] = __builtin_amdgcn_mfma_f32_16x16x32_bf16(a[mi][h], b[ni][h], acc[mi][ni], 0, 0, 0);
    __syncthreads();
  }

  float sv[4], bv[4];
  const int nb0 = Nt * 128 + wc * 64;
#pragma unroll
  for (int ni = 0; ni < 4; ++ni) { int n = nb0 + ni * 16 + l16; sv[ni] = s2[n]; bv[ni] = b2[n]; }
#pragma unroll
  for (int mi = 0; mi < 4; ++mi)
#pragma unroll
    for (int r = 0; r < 4; ++r) {
      int m = Mt * 128 + wr * 64 + mi * 16 + quad * 4 + r;
      bf16* dst = o2 + (size_t)m * CB;
#pragma unroll
      for (int ni = 0; ni < 4; ++ni) {
        int n = nb0 + ni * 16 + l16;
        dst[n] = (bf16)fmaxf(acc[mi][ni][r] * sv[ni] + bv[ni], 0.f);
      }
    }
}

// ---------------- conv3: out[nb][co][p] = relu(s3*o2[p][:]·w3[co][:]+b3+x), fp32 out
__global__ __launch_bounds__(256, 2) void k_conv3(const bf16* __restrict__ o2,
                                                  const bf16* __restrict__ w3,
                                                  const float* __restrict__ s3,
                                                  const float* __restrict__ b3,
                                                  const float* __restrict__ x,
                                                  float* __restrict__ out) {
  __shared__ char smem[32768];
  char* const As = smem;
  char* const Bs = smem + 16384;
  const int tid = threadIdx.x, wave = tid >> 6, lane = tid & 63;
  const int quad = lane >> 4, l16 = lane & 15;
  const int wr = wave >> 1, wc = wave & 1;
  const int Mt = blockIdx.x, Nt = blockIdx.y, nbz = blockIdx.z;

  const bf16* gb[8];
  char* lb;
  if (wave < 2) {
    lb = As + wave * 8192;
#pragma unroll
    for (int i = 0; i < 8; ++i) {
      int g = wave * 8 + i;
      int m = Mt * 128 + (g >> 1) * 16 + l16;               // co < 1024
      gb[i] = w3 + (size_t)m * CB + ((g & 1) * 4 + quad) * 8;
    }
  } else {
    lb = Bs + (wave - 2) * 8192;
#pragma unroll
    for (int i = 0; i < 8; ++i) {
      int g = (wave - 2) * 8 + i;
      int p = Nt * 128 + (g >> 1) * 16 + l16;
      int pc = min(p, HW - 1);                              // clamp; never stored
      gb[i] = o2 + ((size_t)nbz * HW + pc) * CB + ((g & 1) * 4 + quad) * 8;
    }
  }

  f32x4 acc[4][4];
#pragma unroll
  for (int i = 0; i < 4; ++i)
#pragma unroll
    for (int j = 0; j < 4; ++j) acc[i][j] = {0.f, 0.f, 0.f, 0.f};

  const int lo = lane * 16;
  for (int s = 0; s < CB / 64; ++s) {
#pragma unroll
    for (int i = 0; i < 8; ++i) gl16(gb[i] + s * 64, lb + i * 1024);
    __syncthreads();
    bf16x8 a[4][2], b[4][2];
#pragma unroll
    for (int mi = 0; mi < 4; ++mi)
#pragma unroll
      for (int h = 0; h < 2; ++h)
        a[mi][h] = *(const bf16x8*)(As + (((wr * 4 + mi) * 2 + h) * 1024) + lo);
#pragma unroll
    for (int ni = 0; ni < 4; ++ni)
#pragma unroll
      for (int h = 0; h < 2; ++h)
        b[ni][h] = *(const bf16x8*)(Bs + (((wc * 4 + ni) * 2 + h) * 1024) + lo);
#pragma unroll
    for (int h = 0; h < 2; ++h)
#pragma unroll
      for (int mi = 0; mi < 4; ++mi)
#pragma unroll
        for (int ni = 0; ni < 4; ++ni)
          acc[mi][ni] = __builtin_amdgcn_mfma_f32_16x16x32_bf16(a[mi][h], b[ni][h], acc[mi][ni], 0, 0, 0);
    __syncthreads();
  }

#pragma unroll
  for (int mi = 0; mi < 4; ++mi)
#pragma unroll
    for (int r = 0; r < 4; ++r) {
      int m = Mt * 128 + wr * 64 + mi * 16 + quad * 4 + r;  // co
      float sv = s3[m], bvv = b3[m];
      const float* xr = x + ((size_t)nbz * COUT + m) * HW;
      float* orow = out + ((size_t)nbz * COUT + m) * HW;
#pragma unroll
      for (int ni = 0; ni < 4; ++ni) {
        int n = Nt * 128 + wc * 64 + ni * 16 + l16;
        if (n < HW) orow[n] = fmaxf(acc[mi][ni][r] * sv + bvv + xr[n], 0.f);
      }
    }
}

extern "C" void kernel_launch(void* const* d_in, const int* in_sizes, int n_in,
                              void* d_out, int out_size, void* d_ws, size_t ws_size,
                              hipStream_t stream) {
  const float* x  = (const float*)d_in[0];
  const float* w1 = (const float*)d_in[1];
  const float* w2 = (const float*)d_in[2];
  const float* w3 = (const float*)d_in[3];
  const float* s1 = (const float*)d_in[4];
  const float* b1 = (const float*)d_in[5];
  const float* s2 = (const float*)d_in[6];
  const float* b2 = (const float*)d_in[7];
  const float* s3 = (const float*)d_in[8];
  const float* b3 = (const float*)d_in[9];
  float* out = (float*)d_out;

  char* ws = (char*)d_ws;
  // layout (bytes): xT/o2 share [0, 51,380,224) — xT dead before conv2 writes o2.
  // o1p (padded bf16 NHWC 32x900x256) at 51,380,224 (14,745,600 B)
  // w2r at 66,125,824 (1,179,648) | w1b at 67,305,472 (524,288) | w3b at 67,829,760 (524,288)
  bf16* xT  = (bf16*)(ws);
  bf16* o2  = (bf16*)(ws);
  bf16* o1p = (bf16*)(ws + 51380224);
  bf16* w2r = (bf16*)(ws + 66125824);
  bf16* w1b = (bf16*)(ws + 67305472);
  bf16* w3b = (bf16*)(ws + 67829760);

  k_zero<<<dim3(3600, 1, 1), 256, 0, stream>>>((uint4*)o1p, 921600);
  k_transpose<<<dim3(13, 16, NB), 256, 0, stream>>>(x, xT);
  k_w2r<<<dim3(2304, 1, 1), 256, 0, stream>>>(w2, w2r);
  k_cast<<<dim3(256, 1, 1), 256, 0, stream>>>(w1, w1b, CB * CIN);
  k_cast<<<dim3(256, 1, 1), 256, 0, stream>>>(w3, w3b, COUT * CB);
  k_conv1<<<dim3(196, 2, 1), 256, 0, stream>>>(xT, w1b, s1, b1, o1p);
  k_conv2<<<dim3(196, 2, 1), 256, 0, stream>>>(o1p, w2r, s2, b2, o2);
  k_conv3<<<dim3(8, 7, NB), 256, 0, stream>>>(o2, w3b, s3, b3, x, out);
}